// Round 2
// baseline (13234.665 us; speedup 1.0000x reference)
//
#include <hip/hip_runtime.h>
#include <math.h>

// LVCBlock forward, MI355X (gfx950).
// Shapes: B=16, CIN=32, CCOND=100, Lc=512, HOP=8, T=4096, HID=64, NL=4, K=3, COUT=64.
// ALL inputs and the output are float32 (reference dtype). Internal fp32.
//
// Pipeline:
//   k_pred_in : h = lrelu(conv(c, in_w, k=5, pad=2))              (B,64,512)
//   k_res x6  : residual blocks on h
//   k_head    : kbias = conv(h, bias_w, k=3, pad=1)               (B,256,512)
//   k_convt   : xx = convT(lrelu(x), ct_w, s=8, k=16, p=4) + b    (B,32,4096) -> d_out
//   per layer i in 0..3:
//     k_cblock: cb = lrelu(conv(lrelu(xx), cb_ws[i], dil))        (B,32,4096)
//     k_lvc   : fused kernel-head GEMM + LVC einsum + gate, xx += sig*tanh
// xx lives directly in d_out (same size, fully overwritten by k_convt).

#define DEV __device__ __forceinline__

DEV float lrelu(float x) { return x > 0.f ? x : 0.2f * x; }

// ---------------- kernel predictor: input conv (100->64, k=5, pad=2) + lrelu
__global__ void k_pred_in(const float* __restrict__ c, const float* __restrict__ w,
                          const float* __restrict__ bias, float* __restrict__ h) {
    int idx = blockIdx.x * 256 + threadIdx.x;          // 16*64*512
    int l = idx & 511, co = (idx >> 9) & 63, b = idx >> 15;
    float acc = bias[co];
    for (int ci = 0; ci < 100; ++ci) {
        const float* crow = c + (b * 100 + ci) * 512;
        const float* wrow = w + (co * 100 + ci) * 5;
#pragma unroll
        for (int j = 0; j < 5; ++j) {
            int p = l + j - 2;
            if (p >= 0 && p < 512) acc += crow[p] * wrow[j];
        }
    }
    h[idx] = lrelu(acc);
}

// ---------------- residual conv (64->64, k=3, pad=1) + lrelu, optional accumulate
__global__ void k_res(const float* __restrict__ src, const float* __restrict__ w,
                      const float* __restrict__ bias, float* __restrict__ dst,
                      const float* __restrict__ accum) {
    int idx = blockIdx.x * 256 + threadIdx.x;          // 16*64*512
    int l = idx & 511, co = (idx >> 9) & 63, b = idx >> 15;
    float acc = bias[co];
    for (int ci = 0; ci < 64; ++ci) {
        const float* s = src + (b * 64 + ci) * 512;
        const float* wr = w + (co * 64 + ci) * 3;
#pragma unroll
        for (int j = 0; j < 3; ++j) {
            int p = l + j - 1;
            if (p >= 0 && p < 512) acc += s[p] * wr[j];
        }
    }
    float v = lrelu(acc);
    dst[idx] = accum ? accum[idx] + v : v;
}

// ---------------- bias head (64->256, k=3, pad=1), no activation
__global__ void k_head(const float* __restrict__ h, const float* __restrict__ w,
                       const float* __restrict__ bias, float* __restrict__ out) {
    int idx = blockIdx.x * 256 + threadIdx.x;          // 16*256*512
    int l = idx & 511, ch = (idx >> 9) & 255, b = idx >> 17;
    float acc = bias[ch];
    for (int ci = 0; ci < 64; ++ci) {
        const float* s = h + (b * 64 + ci) * 512;
        const float* wr = w + (ch * 64 + ci) * 3;
#pragma unroll
        for (int j = 0; j < 3; ++j) {
            int p = l + j - 1;
            if (p >= 0 && p < 512) acc += s[p] * wr[j];
        }
    }
    out[idx] = acc;  // layout ((b*4+layer)*64+o)*512+l since ch = layer*64+o
}

// ---------------- convt_pre: lrelu then ConvTranspose1d(32->32, k=16, s=8, p=4)
// out[b,co,t] = b[co] + sum_ci sum_{m in {m0, m0+8}} lrelu(x[b,ci,(t+4-m)/8]) * ct_w[ci,co,m]
__global__ void k_convt(const float* __restrict__ x, const float* __restrict__ w,
                        const float* __restrict__ bias, float* __restrict__ xx) {
    int idx = blockIdx.x * 256 + threadIdx.x;          // 16*32*4096
    int t = idx & 4095, co = (idx >> 12) & 31, b = idx >> 17;
    int m0 = (t + 4) & 7, s0 = (t + 4) >> 3;           // tap 0: (s0, m0); tap 1: (s0-1, m0+8)
    float acc = bias[co];
    for (int ci = 0; ci < 32; ++ci) {
        const float* xr = x + (b * 32 + ci) * 512;
        const float* wr = w + (ci * 32 + co) * 16;
        if (s0 < 512) acc += lrelu(xr[s0]) * wr[m0];
        if (s0 >= 1) acc += lrelu(xr[s0 - 1]) * wr[m0 + 8];
    }
    xx[idx] = acc;
}

// ---------------- dilated conv block: lrelu(conv(lrelu(xx), k=3, dil, pad=dil))
__global__ void k_cblock(const float* __restrict__ xx, const float* __restrict__ w,
                         const float* __restrict__ bias, float* __restrict__ cb,
                         int layer, int dil) {
    int idx = blockIdx.x * 256 + threadIdx.x;          // 16*32*4096
    int t = idx & 4095, ci = (idx >> 12) & 31, b = idx >> 17;
    float acc = bias[layer * 32 + ci];
    for (int c2 = 0; c2 < 32; ++c2) {
        const float* s = xx + (b * 32 + c2) * 4096;
        const float* wr = w + ((layer * 32 + ci) * 32 + c2) * 3;
#pragma unroll
        for (int j = 0; j < 3; ++j) {
            int p = t + (j - 1) * dil;
            if (p >= 0 && p < 4096) acc += lrelu(s[p]) * wr[j];
        }
    }
    cb[idx] = lrelu(acc);
}

// ---------------- fused: kernel-head conv (the 77-GFLOP GEMM) + LVC einsum + gate
// Block = (b, 16-l tile). Phase 1: kern[(i,k),o,l] = ker_w row . h window (LDS),
// o-chunked (4 o's/chunk, pairing o and o+32 for the gate). Phase 2: einsum over
// (i,k) with conv-block windows, + kbias, sigmoid*tanh, xx += gate (in place).
__global__ void k_lvc(const float* __restrict__ h, const float* __restrict__ cb,
                      const float* __restrict__ kbias, const float* __restrict__ ker_w,
                      const float* __restrict__ ker_b, float* __restrict__ xx, int layer) {
    __shared__ float Hl[192 * 17];    // Hl[cj][n], cj = hid_c*3 + j, n = local l (pad 17)
    __shared__ float xwb[32 * 132];   // conv-block window: xwb[i][p], p = 0..129
    __shared__ float kc[96 * 68];     // kern chunk: kc[ik*68 + n*4 + oc], oc in [0,4)

    int tid = threadIdx.x;
    int b = blockIdx.x >> 5;
    int l0 = (blockIdx.x & 31) * 16;

    // stage h window (k=3, pad=1): Hl[cj][n] = h[b, cj/3, l0+n + cj%3 - 1]
    for (int v = tid; v < 192 * 16; v += 256) {
        int cj = v >> 4, n = v & 15;
        int cjc = cj / 3, j = cj - cjc * 3;
        int p = l0 + n + j - 1;
        Hl[cj * 17 + n] = (p >= 0 && p < 512) ? h[(b * 64 + cjc) * 512 + p] : 0.f;
    }
    // stage conv-block output window: t in [l0*8-1, l0*8+129)
    int t0 = l0 * 8 - 1;
    for (int v = tid; v < 32 * 130; v += 256) {
        int i = v / 130, p = v - i * 130;
        int t = t0 + p;
        xwb[i * 132 + p] = (t >= 0 && t < 4096) ? cb[(b * 32 + i) * 4096 + t] : 0.f;
    }
    __syncthreads();

    const float* Wl = ker_w + (size_t)layer * 6144 * 192;
    const float* Bl = ker_b + layer * 6144;
    int n = tid & 15, ml = tid >> 4;

    for (int c = 0; c < 16; ++c) {     // 16 o-chunks: {2c, 2c+1, 32+2c, 32+2c+1}
        // ---- phase 1: kern GEMM. thread (n=l, ml) owns 6 ik x 4 oc accumulators.
        float acc[6][4];
        int chl[6][4];
#pragma unroll
        for (int uu = 0; uu < 6; ++uu) {
            int ik = ml + 16 * uu;             // ik = i*3 + k in [0,96)
            int i = ik / 3, k = ik - i * 3;
#pragma unroll
            for (int oc = 0; oc < 4; ++oc) {
                int o = (oc < 2) ? 2 * c + oc : 32 + 2 * c + (oc - 2);
                int ch = (i * 64 + o) * 3 + k;
                chl[uu][oc] = ch * 192;
                acc[uu][oc] = Bl[ch];
            }
        }
        for (int kkb = 0; kkb < 48; ++kkb) {   // K = 192 in steps of 4
            float hreg[4];
#pragma unroll
            for (int u = 0; u < 4; ++u) hreg[u] = Hl[(kkb * 4 + u) * 17 + n];
#pragma unroll
            for (int uu = 0; uu < 6; ++uu) {
#pragma unroll
                for (int oc = 0; oc < 4; ++oc) {
                    float4 w4 = *reinterpret_cast<const float4*>(Wl + chl[uu][oc] + kkb * 4);
                    acc[uu][oc] += w4.x * hreg[0] + w4.y * hreg[1]
                                 + w4.z * hreg[2] + w4.w * hreg[3];
                }
            }
        }
#pragma unroll
        for (int uu = 0; uu < 6; ++uu) {
            int ik = ml + 16 * uu;
#pragma unroll
            for (int oc = 0; oc < 4; ++oc) kc[ik * 68 + n * 4 + oc] = acc[uu][oc];
        }
        __syncthreads();

        // ---- phase 2: einsum + gate. 128 threads: (h8, ll)
        if (tid < 128) {
            int h8 = tid & 7, ll = tid >> 3;
            float a2[4] = {0.f, 0.f, 0.f, 0.f};
            for (int i = 0; i < 32; ++i) {
#pragma unroll
                for (int k = 0; k < 3; ++k) {
                    float xv = xwb[i * 132 + ll * 8 + h8 + k];
                    float4 kv = *reinterpret_cast<const float4*>(&kc[(i * 3 + k) * 68 + ll * 4]);
                    a2[0] += kv.x * xv; a2[1] += kv.y * xv;
                    a2[2] += kv.z * xv; a2[3] += kv.w * xv;
                }
            }
            int lg = l0 + ll;
            int t = lg * 8 + h8;
#pragma unroll
            for (int j = 0; j < 2; ++j) {
                int oa = 2 * c + j, ob = 32 + 2 * c + j;
                float pa = a2[j]     + kbias[((b * 4 + layer) * 64 + oa) * 512 + lg];
                float pb = a2[2 + j] + kbias[((b * 4 + layer) * 64 + ob) * 512 + lg];
                float g = (1.f / (1.f + expf(-pa))) * tanhf(pb);
                int xi = (b * 32 + oa) * 4096 + t;
                xx[xi] = xx[xi] + g;
            }
        }
        __syncthreads();   // kc reused next chunk
    }
}

extern "C" void kernel_launch(void* const* d_in, const int* in_sizes, int n_in,
                              void* d_out, int out_size, void* d_ws, size_t ws_size,
                              hipStream_t stream) {
    const float* x      = (const float*)d_in[0];
    const float* c      = (const float*)d_in[1];
    const float* in_w   = (const float*)d_in[2];
    const float* in_b   = (const float*)d_in[3];
    const float* res_ws = (const float*)d_in[4];
    const float* res_bs = (const float*)d_in[5];
    const float* ker_w  = (const float*)d_in[6];
    const float* ker_b  = (const float*)d_in[7];
    const float* bias_w = (const float*)d_in[8];
    const float* bias_b = (const float*)d_in[9];
    const float* ct_w   = (const float*)d_in[10];
    const float* ct_b   = (const float*)d_in[11];
    const float* cb_ws  = (const float*)d_in[12];
    const float* cb_bs  = (const float*)d_in[13];

    float* ws   = (float*)d_ws;
    float* h    = ws;                 // 16*64*512   = 524288
    float* tmp  = ws + 524288;        // 524288
    float* kb   = ws + 1048576;       // 16*256*512  = 2097152
    float* cb   = ws + 3145728;       // 16*32*4096  = 2097152  (total 21 MB)
    float* xx   = (float*)d_out;      // state tensor lives in d_out (16*32*4096)

    k_pred_in<<<2048, 256, 0, stream>>>(c, in_w, in_b, h);
    for (int j = 0; j < 3; ++j) {
        k_res<<<2048, 256, 0, stream>>>(h,   res_ws + (j * 2 + 0) * 64 * 64 * 3,
                                        res_bs + (j * 2 + 0) * 64, tmp, nullptr);
        k_res<<<2048, 256, 0, stream>>>(tmp, res_ws + (j * 2 + 1) * 64 * 64 * 3,
                                        res_bs + (j * 2 + 1) * 64, h, h);
    }
    k_head<<<8192, 256, 0, stream>>>(h, bias_w, bias_b, kb);
    k_convt<<<8192, 256, 0, stream>>>(x, ct_w, ct_b, xx);

    const int dils[4] = {1, 3, 9, 27};
    for (int L = 0; L < 4; ++L) {
        k_cblock<<<8192, 256, 0, stream>>>(xx, cb_ws, cb_bs, cb, L, dils[L]);
        k_lvc<<<512, 256, 0, stream>>>(h, cb, kb, ker_w, ker_b, xx, L);
    }
}

// Round 7
// 6193.462 us; speedup vs baseline: 2.1369x; 2.1369x over previous
//
#include <hip/hip_runtime.h>
#include <math.h>

// LVCBlock forward, MI355X (gfx950).
// Shapes: B=16, CIN=32, CCOND=100, Lc=512, HOP=8, T=4096, HID=64, NL=4, K=3, COUT=64.
// ALL inputs and the output are float32, ALL math fp32.
//
// R7: R3-R6 post-mortem: the network amplifies perturbations ~50-100x through
// its 4 gated-residual layers; bf16 kernel-head operands (2^-9 seed) land at
// absmax 0.34-0.45 vs threshold 0.117. fp32 kern is REQUIRED (R2 passed at
// 0.0156 = 1 bf16 compare-ulp). So: keep R2's exact fp32 accumulation order,
// fix the L2 thrash (R2: 512 blocks x 4.7MB slice = 2.4GB HBM/dispatch) by
// geometry: block = (b, 64-l tile, half of o-chunks), grid 256 x 512 thr.
// Weights per block = 2.36MB read once; raw 604MB/dispatch worst case (96us),
// XCD round-robin puts same-weight blocks on one XCD -> L2 dedup; compute
// floor 19.3 GFLOP / 157 TF = 123us -> compute-bound. kern produced 48 rows
// per pass into 12KB LDS (8 passes/chunk, phase-2 partial accumulation in
// registers). Static LDS 60KB.

#define DEV __device__ __forceinline__

DEV float lrelu(float x) { return x > 0.f ? x : 0.2f * x; }

// ---------------- kernel predictor: input conv (100->64, k=5, pad=2) + lrelu
__global__ void k_pred_in(const float* __restrict__ c, const float* __restrict__ w,
                          const float* __restrict__ bias, float* __restrict__ h) {
    int idx = blockIdx.x * 256 + threadIdx.x;          // 16*64*512
    int l = idx & 511, co = (idx >> 9) & 63, b = idx >> 15;
    float acc = bias[co];
    for (int ci = 0; ci < 100; ++ci) {
        const float* crow = c + (b * 100 + ci) * 512;
        const float* wrow = w + (co * 100 + ci) * 5;
#pragma unroll
        for (int j = 0; j < 5; ++j) {
            int p = l + j - 2;
            if (p >= 0 && p < 512) acc += crow[p] * wrow[j];
        }
    }
    h[idx] = lrelu(acc);
}

// ---------------- residual conv (64->64, k=3, pad=1) + lrelu, optional accumulate
__global__ void k_res(const float* __restrict__ src, const float* __restrict__ w,
                      const float* __restrict__ bias, float* __restrict__ dst,
                      const float* __restrict__ accum) {
    int idx = blockIdx.x * 256 + threadIdx.x;          // 16*64*512
    int l = idx & 511, co = (idx >> 9) & 63, b = idx >> 15;
    float acc = bias[co];
    for (int ci = 0; ci < 64; ++ci) {
        const float* s = src + (b * 64 + ci) * 512;
        const float* wr = w + (co * 64 + ci) * 3;
#pragma unroll
        for (int j = 0; j < 3; ++j) {
            int p = l + j - 1;
            if (p >= 0 && p < 512) acc += s[p] * wr[j];
        }
    }
    float v = lrelu(acc);
    dst[idx] = accum ? accum[idx] + v : v;
}

// ---------------- bias head, ONE layer's 64 channels (k=3, pad=1), no activation
// out[(b*64+o)*512 + l] = conv_out[b, layer*64+o, l]
__global__ void k_head(const float* __restrict__ h, const float* __restrict__ w,
                       const float* __restrict__ bias, float* __restrict__ out, int layer) {
    int idx = blockIdx.x * 256 + threadIdx.x;          // 16*64*512
    int l = idx & 511, o = (idx >> 9) & 63, b = idx >> 15;
    int ch = layer * 64 + o;
    float acc = bias[ch];
    for (int ci = 0; ci < 64; ++ci) {
        const float* s = h + (b * 64 + ci) * 512;
        const float* wr = w + (ch * 64 + ci) * 3;
#pragma unroll
        for (int j = 0; j < 3; ++j) {
            int p = l + j - 1;
            if (p >= 0 && p < 512) acc += s[p] * wr[j];
        }
    }
    out[idx] = acc;
}

// ---------------- convt_pre: lrelu then ConvTranspose1d(32->32, k=16, s=8, p=4)
__global__ void k_convt(const float* __restrict__ x, const float* __restrict__ w,
                        const float* __restrict__ bias, float* __restrict__ xx) {
    int idx = blockIdx.x * 256 + threadIdx.x;          // 16*32*4096
    int t = idx & 4095, co = (idx >> 12) & 31, b = idx >> 17;
    int m0 = (t + 4) & 7, s0 = (t + 4) >> 3;           // tap 0: (s0, m0); tap 1: (s0-1, m0+8)
    float acc = bias[co];
    for (int ci = 0; ci < 32; ++ci) {
        const float* xr = x + (b * 32 + ci) * 512;
        const float* wr = w + (ci * 32 + co) * 16;
        if (s0 < 512) acc += lrelu(xr[s0]) * wr[m0];
        if (s0 >= 1) acc += lrelu(xr[s0 - 1]) * wr[m0 + 8];
    }
    xx[idx] = acc;
}

// ---------------- dilated conv block: lrelu(conv(lrelu(xx), k=3, dil, pad=dil))
__global__ void k_cblock(const float* __restrict__ xx, const float* __restrict__ w,
                         const float* __restrict__ bias, float* __restrict__ cb,
                         int layer, int dil) {
    int idx = blockIdx.x * 256 + threadIdx.x;          // 16*32*4096
    int t = idx & 4095, ci = (idx >> 12) & 31, b = idx >> 17;
    float acc = bias[layer * 32 + ci];
    for (int c2 = 0; c2 < 32; ++c2) {
        const float* s = xx + (b * 32 + c2) * 4096;
        const float* wr = w + ((layer * 32 + ci) * 32 + c2) * 3;
#pragma unroll
        for (int j = 0; j < 3; ++j) {
            int p = t + (j - 1) * dil;
            if (p >= 0 && p < 4096) acc += lrelu(s[p]) * wr[j];
        }
    }
    cb[idx] = lrelu(acc);
}

// ---------------- fused: kernel-head GEMM (fp32 VALU) + LVC einsum + gate
// Block = (b, 64-l tile lt, half). Chunk c covers o in {2c, 2c+1, 32+2c,
// 32+2c+1}; half 0: c=0..7, half 1: c=8..15 (disjoint xx rows -> no race).
// Row index r in [0,384) per chunk: ik=r>>2 (=i*3+kk), oc=r&3,
// o = 2c + (oc>>1) + 32*(oc&1), ch = (i*64+o)*3+kk.
// Per chunk: 8 passes of 48 rows; pass p: phase 1 computes kern rows
// [48p,48p+48) x 64 locations into kc (fp32, k ascending 0..191 = R2's exact
// order), barrier, phase 2 partially accumulates a[4] over the 12 ik of this
// pass, barrier. Gate after pass 7.
__global__ __launch_bounds__(512) void
k_lvc(const float* __restrict__ h, const float* __restrict__ cb,
      const float* __restrict__ kbL, const float* __restrict__ Wl,
      const float* __restrict__ Bl, float* __restrict__ xx) {
    __shared__ float Hl[192 * 64];      // Hl[cj*64 + n]  (49152 B)
    __shared__ float kc[12 * 64 * 4];   // kc[(ikk*64+n)*4 + oc]  (12288 B)

    int tid = threadIdx.x;
    int half = blockIdx.x & 1;
    int lt = (blockIdx.x >> 1) & 7;
    int b = blockIdx.x >> 4;
    int l0 = lt * 64;

    // stage h window (k=3, pad=1): Hl[cj*64+n] = h[b, cj/3, l0+n + cj%3 - 1]
    for (int v = tid; v < 192 * 64; v += 512) {
        int cj = v >> 6, n = v & 63;
        int ci = cj / 3, jt = cj - ci * 3;
        int p = l0 + n + jt - 1;
        Hl[v] = (p >= 0 && p < 512) ? h[(b * 64 + ci) * 512 + p] : 0.f;
    }
    __syncthreads();

    int rg = tid >> 6, n = tid & 63;            // phase-1: wave rg, location n
    int h8 = tid & 7, n2 = tid >> 3;            // phase-2: hop h8, location n2
    int tglob = (l0 + n2) * 8 + h8;
    int lg = l0 + n2;
    const float* cbb = cb + b * 32 * 4096;
    const float* kbb = kbL + b * 64 * 512;
    float* xxb = xx + b * 32 * 4096;

    for (int c = half * 8; c < half * 8 + 8; ++c) {
        float a0 = 0.f, a1 = 0.f, a2 = 0.f, a3 = 0.f;   // phase-2 partials
        for (int p = 0; p < 8; ++p) {
            // ---- phase 1: rows r = p*48 + rg*6 + q, q in [0,6)
            float acc[6];
            const float* wp[6];
#pragma unroll
            for (int q = 0; q < 6; ++q) {
                int r = p * 48 + rg * 6 + q;
                int ik = r >> 2, oc = r & 3;
                int i = ik / 3, kk = ik - i * 3;
                int o = 2 * c + (oc >> 1) + 32 * (oc & 1);
                int ch = (i * 64 + o) * 3 + kk;
                wp[q] = Wl + (size_t)ch * 192;
                acc[q] = Bl[ch];
            }
            for (int kq = 0; kq < 48; ++kq) {   // k = 0..191 ascending (R2 order)
                float h0 = Hl[(kq * 4 + 0) * 64 + n];
                float h1 = Hl[(kq * 4 + 1) * 64 + n];
                float h2 = Hl[(kq * 4 + 2) * 64 + n];
                float h3 = Hl[(kq * 4 + 3) * 64 + n];
#pragma unroll
                for (int q = 0; q < 6; ++q) {
                    float4 w4 = *reinterpret_cast<const float4*>(wp[q] + kq * 4);
                    acc[q] += w4.x * h0 + w4.y * h1 + w4.z * h2 + w4.w * h3;
                }
            }
#pragma unroll
            for (int q = 0; q < 6; ++q) {
                int rr = rg * 6 + q;            // local row in [0,48)
                kc[((rr >> 2) * 64 + n) * 4 + (rr & 3)] = acc[q];
            }
            __syncthreads();

            // ---- phase 2 partial: ik = p*12 + ikk, ikk in [0,12)
#pragma unroll
            for (int ikk = 0; ikk < 12; ++ikk) {
                int ik = p * 12 + ikk;
                int i = ik / 3, kk = ik - i * 3;
                int tt = tglob + kk - 1;
                float xv = (tt >= 0 && tt < 4096) ? cbb[i * 4096 + tt] : 0.f;
                float4 kv = *reinterpret_cast<const float4*>(&kc[(ikk * 64 + n2) * 4]);
                a0 += kv.x * xv; a1 += kv.y * xv; a2 += kv.z * xv; a3 += kv.w * xv;
            }
            __syncthreads();   // kc reused by next pass
        }
        // ---- gate: oc order {0,1,2,3} -> o {2c, 32+2c, 2c+1, 32+2c+1}
        {
            float pa = a0 + kbb[(2 * c) * 512 + lg];
            float pb = a1 + kbb[(32 + 2 * c) * 512 + lg];
            float g = (1.f / (1.f + expf(-pa))) * tanhf(pb);
            xxb[(2 * c) * 4096 + tglob] += g;
            pa = a2 + kbb[(2 * c + 1) * 512 + lg];
            pb = a3 + kbb[(32 + 2 * c + 1) * 512 + lg];
            g = (1.f / (1.f + expf(-pa))) * tanhf(pb);
            xxb[(2 * c + 1) * 4096 + tglob] += g;
        }
    }
}

extern "C" void kernel_launch(void* const* d_in, const int* in_sizes, int n_in,
                              void* d_out, int out_size, void* d_ws, size_t ws_size,
                              hipStream_t stream) {
    const float* x      = (const float*)d_in[0];
    const float* c      = (const float*)d_in[1];
    const float* in_w   = (const float*)d_in[2];
    const float* in_b   = (const float*)d_in[3];
    const float* res_ws = (const float*)d_in[4];
    const float* res_bs = (const float*)d_in[5];
    const float* ker_w  = (const float*)d_in[6];
    const float* ker_b  = (const float*)d_in[7];
    const float* bias_w = (const float*)d_in[8];
    const float* bias_b = (const float*)d_in[9];
    const float* ct_w   = (const float*)d_in[10];
    const float* ct_b   = (const float*)d_in[11];
    const float* cb_ws  = (const float*)d_in[12];
    const float* cb_bs  = (const float*)d_in[13];

    float* ws   = (float*)d_ws;
    float* h    = ws;                         // [0, 524288)
    float* kbL  = ws + 524288;                // [524288, 1048576)  per-layer bias head
    float* tmp  = ws + 1048576;               // [1048576, 1572864) res-block scratch
    float* cb   = ws + 1572864;               // [1572864, 3670016)
    // high-water 14.68 MB (< 20.97 MB proven by R2's pass)
    float* xx   = (float*)d_out;              // state tensor lives in d_out

    k_pred_in<<<2048, 256, 0, stream>>>(c, in_w, in_b, h);
    for (int j = 0; j < 3; ++j) {
        k_res<<<2048, 256, 0, stream>>>(h,   res_ws + (j * 2 + 0) * 64 * 64 * 3,
                                        res_bs + (j * 2 + 0) * 64, tmp, nullptr);
        k_res<<<2048, 256, 0, stream>>>(tmp, res_ws + (j * 2 + 1) * 64 * 64 * 3,
                                        res_bs + (j * 2 + 1) * 64, h, h);
    }
    k_convt<<<8192, 256, 0, stream>>>(x, ct_w, ct_b, xx);

    const int dils[4] = {1, 3, 9, 27};
    for (int L = 0; L < 4; ++L) {
        k_head<<<2048, 256, 0, stream>>>(h, bias_w, bias_b, kbL, L);
        k_cblock<<<8192, 256, 0, stream>>>(xx, cb_ws, cb_bs, cb, L, dils[L]);
        k_lvc<<<256, 512, 0, stream>>>(h, cb, kbL,
                                       ker_w + (size_t)L * 1179648,
                                       ker_b + (size_t)L * 6144, xx);
    }
}

// Round 8
// 3189.453 us; speedup vs baseline: 4.1495x; 1.9419x over previous
//
#include <hip/hip_runtime.h>
#include <math.h>

// LVCBlock forward, MI355X (gfx950).
// Shapes: B=16, CIN=32, CCOND=100, Lc=512, HOP=8, T=4096, HID=64, NL=4, K=3, COUT=64.
// ALL inputs and the output are float32, ALL math fp32 (bf16 kern seeds get
// amplified ~30x by the gated-residual cascade -> fails the 0.117 threshold;
// established R3-R6).
//
// R8 vs R7 (passed, k_lvc 1500us, VALUBusy 31%, Occupancy 24.5%):
// k_lvc was latency-bound: grid 256 = 1 block/CU (8 waves) and 6 broadcast
// VMEM weight loads per kq with nothing to hide their L2 latency.
//  (1) quarter-split: block does 4 o-chunks, grid 512 -> 2 blocks/CU
//      (16 waves/CU). Quarter in blockIdx&3: round-robin XCD assignment
//      pins a fixed quarter per XCD -> 1.18MB weight slice L2-resident.
//  (2) readfirstlane on the wave-uniform row group -> weight row pointers
//      and Bl loads become scalar (s_load), off the VMEM path.
// Accumulation order bit-identical to R7 (absmax must stay 0.015625).

#define DEV __device__ __forceinline__

DEV float lrelu(float x) { return x > 0.f ? x : 0.2f * x; }

// ---------------- kernel predictor: input conv (100->64, k=5, pad=2) + lrelu
__global__ void k_pred_in(const float* __restrict__ c, const float* __restrict__ w,
                          const float* __restrict__ bias, float* __restrict__ h) {
    int idx = blockIdx.x * 256 + threadIdx.x;          // 16*64*512
    int l = idx & 511, co = (idx >> 9) & 63, b = idx >> 15;
    float acc = bias[co];
    for (int ci = 0; ci < 100; ++ci) {
        const float* crow = c + (b * 100 + ci) * 512;
        const float* wrow = w + (co * 100 + ci) * 5;
#pragma unroll
        for (int j = 0; j < 5; ++j) {
            int p = l + j - 2;
            if (p >= 0 && p < 512) acc += crow[p] * wrow[j];
        }
    }
    h[idx] = lrelu(acc);
}

// ---------------- residual conv (64->64, k=3, pad=1) + lrelu, optional accumulate
__global__ void k_res(const float* __restrict__ src, const float* __restrict__ w,
                      const float* __restrict__ bias, float* __restrict__ dst,
                      const float* __restrict__ accum) {
    int idx = blockIdx.x * 256 + threadIdx.x;          // 16*64*512
    int l = idx & 511, co = (idx >> 9) & 63, b = idx >> 15;
    float acc = bias[co];
    for (int ci = 0; ci < 64; ++ci) {
        const float* s = src + (b * 64 + ci) * 512;
        const float* wr = w + (co * 64 + ci) * 3;
#pragma unroll
        for (int j = 0; j < 3; ++j) {
            int p = l + j - 1;
            if (p >= 0 && p < 512) acc += s[p] * wr[j];
        }
    }
    float v = lrelu(acc);
    dst[idx] = accum ? accum[idx] + v : v;
}

// ---------------- bias head, ONE layer's 64 channels (k=3, pad=1), no activation
__global__ void k_head(const float* __restrict__ h, const float* __restrict__ w,
                       const float* __restrict__ bias, float* __restrict__ out, int layer) {
    int idx = blockIdx.x * 256 + threadIdx.x;          // 16*64*512
    int l = idx & 511, o = (idx >> 9) & 63, b = idx >> 15;
    int ch = layer * 64 + o;
    float acc = bias[ch];
    for (int ci = 0; ci < 64; ++ci) {
        const float* s = h + (b * 64 + ci) * 512;
        const float* wr = w + (ch * 64 + ci) * 3;
#pragma unroll
        for (int j = 0; j < 3; ++j) {
            int p = l + j - 1;
            if (p >= 0 && p < 512) acc += s[p] * wr[j];
        }
    }
    out[idx] = acc;   // idx = (b*64+o)*512 + l
}

// ---------------- convt_pre: lrelu then ConvTranspose1d(32->32, k=16, s=8, p=4)
__global__ void k_convt(const float* __restrict__ x, const float* __restrict__ w,
                        const float* __restrict__ bias, float* __restrict__ xx) {
    int idx = blockIdx.x * 256 + threadIdx.x;          // 16*32*4096
    int t = idx & 4095, co = (idx >> 12) & 31, b = idx >> 17;
    int m0 = (t + 4) & 7, s0 = (t + 4) >> 3;           // tap 0: (s0, m0); tap 1: (s0-1, m0+8)
    float acc = bias[co];
    for (int ci = 0; ci < 32; ++ci) {
        const float* xr = x + (b * 32 + ci) * 512;
        const float* wr = w + (ci * 32 + co) * 16;
        if (s0 < 512) acc += lrelu(xr[s0]) * wr[m0];
        if (s0 >= 1) acc += lrelu(xr[s0 - 1]) * wr[m0 + 8];
    }
    xx[idx] = acc;
}

// ---------------- dilated conv block: lrelu(conv(lrelu(xx), k=3, dil, pad=dil))
__global__ void k_cblock(const float* __restrict__ xx, const float* __restrict__ w,
                         const float* __restrict__ bias, float* __restrict__ cb,
                         int layer, int dil) {
    int idx = blockIdx.x * 256 + threadIdx.x;          // 16*32*4096
    int t = idx & 4095, ci = (idx >> 12) & 31, b = idx >> 17;
    float acc = bias[layer * 32 + ci];
    for (int c2 = 0; c2 < 32; ++c2) {
        const float* s = xx + (b * 32 + c2) * 4096;
        const float* wr = w + ((layer * 32 + ci) * 32 + c2) * 3;
#pragma unroll
        for (int j = 0; j < 3; ++j) {
            int p = t + (j - 1) * dil;
            if (p >= 0 && p < 4096) acc += lrelu(s[p]) * wr[j];
        }
    }
    cb[idx] = lrelu(acc);
}

// ---------------- fused: kernel-head GEMM (fp32 VALU) + LVC einsum + gate
// Block = (b, 64-l tile lt, quarter). Chunk c covers o in {2c, 2c+1, 32+2c,
// 32+2c+1}; quarter qtr handles c = 4*qtr .. 4*qtr+3 (disjoint xx rows).
// Per chunk: 8 passes of 48 rows (8 waves x 6 rows); phase 1 fills kc for
// this pass's 12 ik, barrier, phase 2 partial-accumulates, barrier.
// Accumulation: k ascending inside rows, ik ascending across passes (= R7).
__global__ __launch_bounds__(512) void
k_lvc(const float* __restrict__ h, const float* __restrict__ cb,
      const float* __restrict__ kbL, const float* __restrict__ Wl,
      const float* __restrict__ Bl, float* __restrict__ xx) {
    __shared__ float Hl[192 * 64];      // Hl[cj*64 + n]  (49152 B)
    __shared__ float kc[12 * 64 * 4];   // kc[(ikk*64+n)*4 + oc]  (12288 B)

    int tid = threadIdx.x;
    int qtr = blockIdx.x & 3;           // low bits: fixed quarter per XCD (%8 rr)
    int lt = (blockIdx.x >> 2) & 7;
    int b = blockIdx.x >> 5;
    int l0 = lt * 64;

    // stage h window (k=3, pad=1): Hl[cj*64+n] = h[b, cj/3, l0+n + cj%3 - 1]
    for (int v = tid; v < 192 * 64; v += 512) {
        int cj = v >> 6, n = v & 63;
        int ci = cj / 3, jt = cj - ci * 3;
        int p = l0 + n + jt - 1;
        Hl[v] = (p >= 0 && p < 512) ? h[(b * 64 + ci) * 512 + p] : 0.f;
    }
    __syncthreads();

    // rg is value-uniform per wave; readfirstlane makes it compiler-uniform so
    // weight row addresses / Bl loads go scalar (s_load), off the VMEM path.
    int rg = __builtin_amdgcn_readfirstlane(tid >> 6);
    int n = tid & 63;                           // phase-1 location
    int h8 = tid & 7, n2 = tid >> 3;            // phase-2: hop h8, location n2
    int tglob = (l0 + n2) * 8 + h8;
    int lg = l0 + n2;
    const float* cbb = cb + b * 32 * 4096;
    const float* kbb = kbL + b * 64 * 512;
    float* xxb = xx + b * 32 * 4096;

    for (int c = qtr * 4; c < qtr * 4 + 4; ++c) {
        float a0 = 0.f, a1 = 0.f, a2 = 0.f, a3 = 0.f;   // phase-2 partials
        for (int p = 0; p < 8; ++p) {
            // ---- phase 1: rows r = p*48 + rg*6 + q, q in [0,6)
            float acc[6];
            const float* wp[6];
#pragma unroll
            for (int q = 0; q < 6; ++q) {
                int r = p * 48 + rg * 6 + q;
                int ik = r >> 2, oc = r & 3;
                int i = ik / 3, kk = ik - i * 3;
                int o = 2 * c + (oc >> 1) + 32 * (oc & 1);
                int ch = (i * 64 + o) * 3 + kk;          // uniform (rg scalar)
                wp[q] = Wl + (size_t)ch * 192;
                acc[q] = Bl[ch];
            }
#pragma unroll 2
            for (int kq = 0; kq < 48; ++kq) {   // k = 0..191 ascending (R2 order)
                float h0 = Hl[(kq * 4 + 0) * 64 + n];
                float h1 = Hl[(kq * 4 + 1) * 64 + n];
                float h2 = Hl[(kq * 4 + 2) * 64 + n];
                float h3 = Hl[(kq * 4 + 3) * 64 + n];
#pragma unroll
                for (int q = 0; q < 6; ++q) {
                    float4 w4 = *reinterpret_cast<const float4*>(wp[q] + kq * 4);
                    acc[q] += w4.x * h0 + w4.y * h1 + w4.z * h2 + w4.w * h3;
                }
            }
#pragma unroll
            for (int q = 0; q < 6; ++q) {
                int rr = rg * 6 + q;            // local row in [0,48)
                kc[((rr >> 2) * 64 + n) * 4 + (rr & 3)] = acc[q];
            }
            __syncthreads();

            // ---- phase 2 partial: ik = p*12 + ikk, ikk in [0,12)
#pragma unroll
            for (int ikk = 0; ikk < 12; ++ikk) {
                int ik = p * 12 + ikk;
                int i = ik / 3, kk = ik - i * 3;
                int tt = tglob + kk - 1;
                float xv = (tt >= 0 && tt < 4096) ? cbb[i * 4096 + tt] : 0.f;
                float4 kv = *reinterpret_cast<const float4*>(&kc[(ikk * 64 + n2) * 4]);
                a0 += kv.x * xv; a1 += kv.y * xv; a2 += kv.z * xv; a3 += kv.w * xv;
            }
            __syncthreads();   // kc reused by next pass
        }
        // ---- gate: oc order {0,1,2,3} -> o {2c, 32+2c, 2c+1, 32+2c+1}
        {
            float pa = a0 + kbb[(2 * c) * 512 + lg];
            float pb = a1 + kbb[(32 + 2 * c) * 512 + lg];
            float g = (1.f / (1.f + expf(-pa))) * tanhf(pb);
            xxb[(2 * c) * 4096 + tglob] += g;
            pa = a2 + kbb[(2 * c + 1) * 512 + lg];
            pb = a3 + kbb[(32 + 2 * c + 1) * 512 + lg];
            g = (1.f / (1.f + expf(-pa))) * tanhf(pb);
            xxb[(2 * c + 1) * 4096 + tglob] += g;
        }
    }
}

extern "C" void kernel_launch(void* const* d_in, const int* in_sizes, int n_in,
                              void* d_out, int out_size, void* d_ws, size_t ws_size,
                              hipStream_t stream) {
    const float* x      = (const float*)d_in[0];
    const float* c      = (const float*)d_in[1];
    const float* in_w   = (const float*)d_in[2];
    const float* in_b   = (const float*)d_in[3];
    const float* res_ws = (const float*)d_in[4];
    const float* res_bs = (const float*)d_in[5];
    const float* ker_w  = (const float*)d_in[6];
    const float* ker_b  = (const float*)d_in[7];
    const float* bias_w = (const float*)d_in[8];
    const float* bias_b = (const float*)d_in[9];
    const float* ct_w   = (const float*)d_in[10];
    const float* ct_b   = (const float*)d_in[11];
    const float* cb_ws  = (const float*)d_in[12];
    const float* cb_bs  = (const float*)d_in[13];

    float* ws   = (float*)d_ws;
    float* h    = ws;                         // [0, 524288)
    float* kbL  = ws + 524288;                // [524288, 1048576)  per-layer bias head
    float* tmp  = ws + 1048576;               // [1048576, 1572864) res-block scratch
    float* cb   = ws + 1572864;               // [1572864, 3670016)
    // high-water 14.68 MB (< 20.97 MB proven by R2's pass)
    float* xx   = (float*)d_out;              // state tensor lives in d_out

    k_pred_in<<<2048, 256, 0, stream>>>(c, in_w, in_b, h);
    for (int j = 0; j < 3; ++j) {
        k_res<<<2048, 256, 0, stream>>>(h,   res_ws + (j * 2 + 0) * 64 * 64 * 3,
                                        res_bs + (j * 2 + 0) * 64, tmp, nullptr);
        k_res<<<2048, 256, 0, stream>>>(tmp, res_ws + (j * 2 + 1) * 64 * 64 * 3,
                                        res_bs + (j * 2 + 1) * 64, h, h);
    }
    k_convt<<<8192, 256, 0, stream>>>(x, ct_w, ct_b, xx);

    const int dils[4] = {1, 3, 9, 27};
    for (int L = 0; L < 4; ++L) {
        k_head<<<2048, 256, 0, stream>>>(h, bias_w, bias_b, kbL, L);
        k_cblock<<<8192, 256, 0, stream>>>(xx, cb_ws, cb_bs, cb, L, dils[L]);
        k_lvc<<<512, 512, 0, stream>>>(h, cb, kbL,
                                       ker_w + (size_t)L * 1179648,
                                       ker_b + (size_t)L * 6144, xx);
    }
}